// Round 7
// baseline (418.577 us; speedup 1.0000x reference)
//
#include <hip/hip_runtime.h>
#include <hip/hip_bf16.h>

// ---------------------------------------------------------------------------
// MultiheadAttention fused pipeline for MI355X (gfx950)
// B=2, S=S'=2048, H=16, D_MODEL=1024, dk=dv=64
// outputs: out [2,2048,1024] fp32, attn [2,16,2048,2048] fp32 (concat in d_out)
// ---------------------------------------------------------------------------

typedef __bf16 bf16x8 __attribute__((ext_vector_type(8)));
typedef __bf16 bf16x4 __attribute__((ext_vector_type(4)));
typedef float  f32x4  __attribute__((ext_vector_type(4)));
typedef float  f32x16 __attribute__((ext_vector_type(16)));

#define NUM_HEAD 16
#define SEQ 2048
#define DMODEL 1024
#define DK 64
#define MROWS 4096      // B*S

__device__ __forceinline__ void gload_lds16(const void* g, void* l) {
    __builtin_amdgcn_global_load_lds((const __attribute__((address_space(1))) void*)g,
                                     (__attribute__((address_space(3))) void*)l, 16, 0, 0);
}

// ---------------------------------------------------------------------------
// LayerNorm(query) -> bf16, one block (256 thr) per row of 1024
// ---------------------------------------------------------------------------
__global__ __launch_bounds__(256) void ln_kernel(const float* __restrict__ x,
                                                 const float* __restrict__ g,
                                                 const float* __restrict__ bt,
                                                 __bf16* __restrict__ y) {
    int row = blockIdx.x, tid = threadIdx.x;
    __shared__ float red[2][4];
    float4 v = ((const float4*)(x + (size_t)row * DMODEL))[tid];
    float s  = v.x + v.y + v.z + v.w;
    float sq = v.x * v.x + v.y * v.y + v.z * v.z + v.w * v.w;
    #pragma unroll
    for (int o = 32; o; o >>= 1) { s += __shfl_xor(s, o, 64); sq += __shfl_xor(sq, o, 64); }
    int wv = tid >> 6;
    if ((tid & 63) == 0) { red[0][wv] = s; red[1][wv] = sq; }
    __syncthreads();
    s  = red[0][0] + red[0][1] + red[0][2] + red[0][3];
    sq = red[1][0] + red[1][1] + red[1][2] + red[1][3];
    float mu  = s * (1.0f / DMODEL);
    float var = sq * (1.0f / DMODEL) - mu * mu;
    float rs  = rsqrtf(var + 1e-6f);
    float4 gg = ((const float4*)g)[tid];
    float4 bb = ((const float4*)bt)[tid];
    bf16x4 o;
    o[0] = (__bf16)((v.x - mu) * rs * gg.x + bb.x);
    o[1] = (__bf16)((v.y - mu) * rs * gg.y + bb.y);
    o[2] = (__bf16)((v.z - mu) * rs * gg.z + bb.z);
    o[3] = (__bf16)((v.w - mu) * rs * gg.w + bb.w);
    *(bf16x4*)&y[(size_t)row * DMODEL + tid * 4] = o;
}

// ---------------------------------------------------------------------------
// All fp32->bf16 casts in one dispatch.  Total float4 = 3,145,728 -> grid 12288.
// ---------------------------------------------------------------------------
__global__ __launch_bounds__(256) void cast_all(const float* __restrict__ key,
                                                const float* __restrict__ value,
                                                const float* __restrict__ wq,
                                                const float* __restrict__ wk,
                                                const float* __restrict__ wv,
                                                const float* __restrict__ wo,
                                                __bf16* kb, __bf16* vb, __bf16* wqb,
                                                __bf16* wkb, __bf16* wvb, __bf16* wob) {
    int i = blockIdx.x * 256 + threadIdx.x;     // float4 index, [0, 3145728)
    const float* src; __bf16* dst; int off;
    if (i < 1048576)      { src = key;   dst = kb;  off = i; }
    else if (i < 2097152) { src = value; dst = vb;  off = i - 1048576; }
    else if (i < 2359296) { src = wq;    dst = wqb; off = i - 2097152; }
    else if (i < 2621440) { src = wk;    dst = wkb; off = i - 2359296; }
    else if (i < 2883584) { src = wv;    dst = wvb; off = i - 2621440; }
    else                  { src = wo;    dst = wob; off = i - 2883584; }
    float4 v = ((const float4*)src)[off];
    bf16x4 o = {(__bf16)v.x, (__bf16)v.y, (__bf16)v.z, (__bf16)v.w};
    *(bf16x4*)&dst[(size_t)off * 4] = o;
}

// ---------------------------------------------------------------------------
// Fused Q/K/V projections. 768 blocks (3 modes x 256 tiles) -> 3 blocks/CU.
// ---------------------------------------------------------------------------
__global__ __launch_bounds__(256) void qkv_proj(const __bf16* __restrict__ qn,
                                                const __bf16* __restrict__ kb,
                                                const __bf16* __restrict__ vb,
                                                const __bf16* __restrict__ wqb,
                                                const __bf16* __restrict__ wkb,
                                                const __bf16* __restrict__ wvb,
                                                __bf16* __restrict__ Qp,
                                                __bf16* __restrict__ Kp,
                                                __bf16* __restrict__ Vt) {
    const int Kd = 1024;
    __shared__ __bf16 As[128][32];
    __shared__ __bf16 Bs[128][32];
    int mode = blockIdx.x >> 8;               // 0,1,2
    int t = blockIdx.x & 255;
    int tm = t >> 3, tn = t & 7;              // 32 x 8 tiles (N=1024)
    int tid = threadIdx.x, lane = tid & 63, wv = tid >> 6;
    int wr = (wv >> 1) * 64, wc = (wv & 1) * 64;
    int lr = lane & 15, lg = lane >> 4;
    int r0 = tid >> 2, c0 = (tid & 3) * 8;

    const __bf16* A = (mode == 0) ? qn : (mode == 1) ? kb : vb;
    const __bf16* W = (mode == 0) ? wqb : (mode == 1) ? wkb : wvb;

    f32x4 acc[4][4] = {};
    const __bf16* Arow = A + (size_t)(tm * 128) * Kd;
    const __bf16* Brow = W + (size_t)(tn * 128) * Kd;

    for (int kt = 0; kt < Kd; kt += 32) {
        __syncthreads();
        gload_lds16(&Arow[(size_t)r0 * Kd + kt + c0],        &As[r0][c0]);
        gload_lds16(&Arow[(size_t)(r0 + 64) * Kd + kt + c0], &As[r0 + 64][c0]);
        gload_lds16(&Brow[(size_t)r0 * Kd + kt + c0],        &Bs[r0][c0]);
        gload_lds16(&Brow[(size_t)(r0 + 64) * Kd + kt + c0], &Bs[r0 + 64][c0]);
        __syncthreads();
        bf16x8 af[4], bg[4];
        #pragma unroll
        for (int m = 0; m < 4; ++m) af[m] = *(bf16x8*)&As[wr + m * 16 + lr][lg * 8];
        #pragma unroll
        for (int n = 0; n < 4; ++n) bg[n] = *(bf16x8*)&Bs[wc + n * 16 + lr][lg * 8];
        #pragma unroll
        for (int m = 0; m < 4; ++m)
            #pragma unroll
            for (int n = 0; n < 4; ++n)
                acc[m][n] = __builtin_amdgcn_mfma_f32_16x16x32_bf16(af[m], bg[n], acc[m][n], 0, 0, 0);
    }

    if (mode < 2) {
        float scale = (mode == 0) ? 0.125f : 1.0f;
        __bf16* C = (mode == 0) ? Qp : Kp;
        #pragma unroll
        for (int m = 0; m < 4; ++m)
            #pragma unroll
            for (int n = 0; n < 4; ++n)
                #pragma unroll
                for (int r = 0; r < 4; ++r) {
                    int grow = tm * 128 + wr + m * 16 + lg * 4 + r;
                    int gcol = tn * 128 + wc + n * 16 + lr;
                    int b = grow >> 11, ss = grow & 2047, h = gcol >> 6, d = gcol & 63;
                    C[((size_t)(b * NUM_HEAD + h) * SEQ + ss) * DK + d] = (__bf16)(acc[m][n][r] * scale);
                }
    } else {
        #pragma unroll
        for (int m = 0; m < 4; ++m)
            #pragma unroll
            for (int n = 0; n < 4; ++n)
                #pragma unroll
                for (int r = 0; r < 4; ++r) {
                    int grow = tm * 128 + wr + m * 16 + lg * 4 + r;
                    int gcol = tn * 128 + wc + n * 16 + lr;
                    int b = grow >> 11, ss = grow & 2047, h = gcol >> 6, d = gcol & 63;
                    Vt[((size_t)(b * NUM_HEAD + h) * DK + d) * SEQ + ss] = (__bf16)acc[m][n][r];
                }
    }
}

// ---------------------------------------------------------------------------
// Output projection + residual, 256 blocks.
// ---------------------------------------------------------------------------
__global__ __launch_bounds__(256) void out_gemm(const __bf16* __restrict__ A,
                                                const __bf16* __restrict__ Bw,
                                                const float* __restrict__ residual,
                                                float* __restrict__ out) {
    const int Kd = 1024;
    __shared__ __bf16 As[128][32];
    __shared__ __bf16 Bs[128][32];
    int tm = blockIdx.x >> 3, tn = blockIdx.x & 7;
    int tid = threadIdx.x, lane = tid & 63, wv = tid >> 6;
    int wr = (wv >> 1) * 64, wc = (wv & 1) * 64;
    int lr = lane & 15, lg = lane >> 4;
    int r0 = tid >> 2, c0 = (tid & 3) * 8;

    f32x4 acc[4][4] = {};
    const __bf16* Arow = A  + (size_t)(tm * 128) * Kd;
    const __bf16* Brow = Bw + (size_t)(tn * 128) * Kd;

    for (int kt = 0; kt < Kd; kt += 32) {
        __syncthreads();
        gload_lds16(&Arow[(size_t)r0 * Kd + kt + c0],        &As[r0][c0]);
        gload_lds16(&Arow[(size_t)(r0 + 64) * Kd + kt + c0], &As[r0 + 64][c0]);
        gload_lds16(&Brow[(size_t)r0 * Kd + kt + c0],        &Bs[r0][c0]);
        gload_lds16(&Brow[(size_t)(r0 + 64) * Kd + kt + c0], &Bs[r0 + 64][c0]);
        __syncthreads();
        bf16x8 af[4], bg[4];
        #pragma unroll
        for (int m = 0; m < 4; ++m) af[m] = *(bf16x8*)&As[wr + m * 16 + lr][lg * 8];
        #pragma unroll
        for (int n = 0; n < 4; ++n) bg[n] = *(bf16x8*)&Bs[wc + n * 16 + lr][lg * 8];
        #pragma unroll
        for (int m = 0; m < 4; ++m)
            #pragma unroll
            for (int n = 0; n < 4; ++n)
                acc[m][n] = __builtin_amdgcn_mfma_f32_16x16x32_bf16(af[m], bg[n], acc[m][n], 0, 0, 0);
    }

    #pragma unroll
    for (int m = 0; m < 4; ++m)
        #pragma unroll
        for (int n = 0; n < 4; ++n)
            #pragma unroll
            for (int r = 0; r < 4; ++r) {
                int grow = tm * 128 + wr + m * 16 + lg * 4 + r;
                int gcol = tn * 128 + wc + n * 16 + lr;
                size_t idx = (size_t)grow * DMODEL + gcol;
                out[idx] = acc[m][n][r] + residual[idx];
            }
}

// ---------------------------------------------------------------------------
// Attention stage A: softmax stats (m, 1/l) per q-row.
// Verified round-5 phase A structure: 2048 blocks (XCD-chunked) x 4 waves;
// wave wv owns keys [wv*512, +512), online (m,l) with tree-max + defer-max,
// shfl_xor(32) half-merge + LDS cross-wave merge. ~90 VGPR -> 4 blocks/CU.
// ---------------------------------------------------------------------------
__global__ __launch_bounds__(256) void attn_stats(const __bf16* __restrict__ Qp,
                                                  const __bf16* __restrict__ Kp,
                                                  float* __restrict__ mrow,
                                                  float* __restrict__ invlrow) {
    __shared__ float mlred[4][32][2];

    int bid = blockIdx.x;
    int wid = (bid & 7) * 256 + (bid >> 3);   // XCD-chunked
    int bh = wid >> 6;
    int qbase = (wid & 63) * 32;
    int tid = threadIdx.x, lane = tid & 63, wv = tid >> 6;
    int l31 = lane & 31, hi = lane >> 5;

    const __bf16* Qh = Qp + ((size_t)bh * SEQ + qbase) * DK;
    const __bf16* Kh = Kp + (size_t)bh * SEQ * DK;

    bf16x8 qf[4];
    #pragma unroll
    for (int s = 0; s < 4; ++s)
        qf[s] = *(const bf16x8*)&Qh[(size_t)l31 * DK + s * 16 + hi * 8];

    int kbase = wv * 512;

    float m = -1e30f, lsum = 0.f;
    for (int t = 0; t < 16; ++t) {
        int k0 = kbase + t * 32;
        bf16x8 kf[4];
        #pragma unroll
        for (int s = 0; s < 4; ++s)
            kf[s] = *(const bf16x8*)&Kh[(size_t)(k0 + l31) * DK + s * 16 + hi * 8];
        f32x16 d;
        #pragma unroll
        for (int r = 0; r < 16; ++r) d[r] = 0.f;
        #pragma unroll
        for (int s = 0; s < 4; ++s)
            d = __builtin_amdgcn_mfma_f32_32x32x16_bf16(kf[s], qf[s], d, 0, 0, 0);
        float m8[8];
        #pragma unroll
        for (int r = 0; r < 8; ++r) m8[r] = fmaxf(d[r], d[r + 8]);
        #pragma unroll
        for (int r = 0; r < 4; ++r) m8[r] = fmaxf(m8[r], m8[r + 4]);
        float pmax = fmaxf(fmaxf(m8[0], m8[1]), fmaxf(m8[2], m8[3]));
        if (!__all(pmax - m <= 8.0f)) {    // defer-max: rescale rarely
            float nm = fmaxf(m, pmax);
            lsum *= __expf(m - nm);
            m = nm;
        }
        float es[4] = {0.f, 0.f, 0.f, 0.f};
        #pragma unroll
        for (int r = 0; r < 16; ++r) es[r & 3] += __expf(d[r] - m);
        lsum += (es[0] + es[1]) + (es[2] + es[3]);
    }
    {   // merge interleaved key-halves (lane ^ 32, same q)
        float mo = __shfl_xor(m, 32, 64);
        float lo_ = __shfl_xor(lsum, 32, 64);
        float nm = fmaxf(m, mo);
        lsum = lsum * __expf(m - nm) + lo_ * __expf(mo - nm);
        m = nm;
    }
    if (hi == 0) { mlred[wv][l31][0] = m; mlred[wv][l31][1] = lsum; }
    __syncthreads();
    {   // merge across 4 waves (disjoint key ranges)
        float fm = -1e30f;
        #pragma unroll
        for (int w = 0; w < 4; ++w) fm = fmaxf(fm, mlred[w][l31][0]);
        float fl = 0.f;
        #pragma unroll
        for (int w = 0; w < 4; ++w) fl += mlred[w][l31][1] * __expf(mlred[w][l31][0] - fm);
        m = fm;
        lsum = fl;
    }
    if (tid < 32) {
        mrow[(size_t)bh * SEQ + qbase + tid]    = m;
        invlrow[(size_t)bh * SEQ + qbase + tid] = 1.0f / lsum;
    }
}

// ---------------------------------------------------------------------------
// Attention stage B: P computation + write + PV. One WAVE owns one 32-row
// q-tile x ALL 2048 keys: no barriers, no LDS, no cross-wave reduction.
// 512 blocks (XCD-chunked) x 4 independent waves. Per 32-key tile (verified
// round-5/6 fragment): QK^T MFMA -> p=exp(s-m)*invl -> direct f32x4 P-store
// -> bf16 pack + shfl_xor(32) -> PV MFMA into persistent o0/o1.
// ---------------------------------------------------------------------------
__global__ __launch_bounds__(256) void attn_pv(const __bf16* __restrict__ Qp,
                                               const __bf16* __restrict__ Kp,
                                               const __bf16* __restrict__ Vt,
                                               const float* __restrict__ mrow,
                                               const float* __restrict__ invlrow,
                                               float* __restrict__ attn_out,
                                               __bf16* __restrict__ out_heads) {
    int bid = blockIdx.x;                       // [0,512)
    int wid = (bid & 7) * 64 + (bid >> 3);      // XCD-chunked: 4 heads per XCD
    int unit = wid * 4 + (threadIdx.x >> 6);    // q-tile unit in [0,2048)
    int bh = unit >> 6;
    int qbase = (unit & 63) * 32;
    int lane = threadIdx.x & 63, l31 = lane & 31, hi = lane >> 5;

    const __bf16* Qh = Qp + ((size_t)bh * SEQ + qbase) * DK;
    const __bf16* Kh = Kp + (size_t)bh * SEQ * DK;
    const __bf16* Vh = Vt + (size_t)bh * DK * SEQ;

    bf16x8 qf[4];
    #pragma unroll
    for (int s = 0; s < 4; ++s)
        qf[s] = *(const bf16x8*)&Qh[(size_t)l31 * DK + s * 16 + hi * 8];

    float m    = mrow[(size_t)bh * SEQ + qbase + l31];
    float invl = invlrow[(size_t)bh * SEQ + qbase + l31];

    float* attn_base = attn_out + ((size_t)bh * SEQ + qbase) * SEQ;
    f32x16 o0, o1;
    #pragma unroll
    for (int r = 0; r < 16; ++r) { o0[r] = 0.f; o1[r] = 0.f; }

    for (int t = 0; t < 64; ++t) {
        int k0 = t * 32;
        bf16x8 kf[4];
        #pragma unroll
        for (int s = 0; s < 4; ++s)
            kf[s] = *(const bf16x8*)&Kh[(size_t)(k0 + l31) * DK + s * 16 + hi * 8];
        f32x16 d;
        #pragma unroll
        for (int r = 0; r < 16; ++r) d[r] = 0.f;
        #pragma unroll
        for (int s = 0; s < 4; ++s)
            d = __builtin_amdgcn_mfma_f32_32x32x16_bf16(kf[s], qf[s], d, 0, 0, 0);

        float p[16];
        #pragma unroll
        for (int r = 0; r < 16; ++r) p[r] = __expf(d[r] - m) * invl;

        // direct P write: reg quad q4 = keys k0 + 8*q4 + 4*hi + (0..3), row q=l31
        #pragma unroll
        for (int q4 = 0; q4 < 4; ++q4) {
            f32x4 v4 = {p[4 * q4], p[4 * q4 + 1], p[4 * q4 + 2], p[4 * q4 + 3]};
            *(f32x4*)&attn_base[(size_t)l31 * SEQ + k0 + 8 * q4 + 4 * hi] = v4;
        }

        // pack P to bf16 pair-words: w[i] = keys(reg 2i, 2i+1)
        unsigned int w[8];
        #pragma unroll
        for (int i = 0; i < 8; ++i) {
            union { __bf16 h[2]; unsigned int u; } bw;
            bw.h[0] = (__bf16)p[2 * i];
            bw.h[1] = (__bf16)p[2 * i + 1];
            w[i] = bw.u;
        }
        #pragma unroll
        for (int slot = 0; slot < 2; ++slot) {
            unsigned int w0 = w[4 * slot], w1 = w[4 * slot + 1], w2 = w[4 * slot + 2], w3 = w[4 * slot + 3];
            unsigned int s0 = (unsigned int)__shfl_xor((int)w0, 32, 64);
            unsigned int s1 = (unsigned int)__shfl_xor((int)w1, 32, 64);
            unsigned int s2 = (unsigned int)__shfl_xor((int)w2, 32, 64);
            unsigned int s3 = (unsigned int)__shfl_xor((int)w3, 32, 64);
            union { unsigned int u[4]; bf16x8 v; } pa;
            pa.u[0] = hi ? s2 : w0;
            pa.u[1] = hi ? s3 : w1;
            pa.u[2] = hi ? w2 : s0;
            pa.u[3] = hi ? w3 : s1;
            #pragma unroll
            for (int dvb = 0; dvb < 2; ++dvb) {
                bf16x8 vf = *(const bf16x8*)&Vh[(size_t)(dvb * 32 + l31) * SEQ + k0 + slot * 16 + hi * 8];
                if (dvb == 0) o0 = __builtin_amdgcn_mfma_f32_32x32x16_bf16(pa.v, vf, o0, 0, 0, 0);
                else          o1 = __builtin_amdgcn_mfma_f32_32x32x16_bf16(pa.v, vf, o1, 0, 0, 0);
            }
        }
    }

    // O write: wave owns all keys -> complete O, no reduction
    int b = bh >> 4, h = bh & 15;
    #pragma unroll
    for (int r = 0; r < 16; ++r) {
        int q = (r & 3) + 8 * (r >> 2) + 4 * hi;
        __bf16* orow = &out_heads[((size_t)(b * SEQ + qbase + q)) * DMODEL + h * DK];
        orow[l31]      = (__bf16)o0[r];
        orow[32 + l31] = (__bf16)o1[r];
    }
}

// ---------------------------------------------------------------------------
extern "C" void kernel_launch(void* const* d_in, const int* in_sizes, int n_in,
                              void* d_out, int out_size, void* d_ws, size_t ws_size,
                              hipStream_t stream) {
    const float* query = (const float*)d_in[0];
    const float* key   = (const float*)d_in[1];
    const float* value = (const float*)d_in[2];
    const float* w_q   = (const float*)d_in[3];
    const float* w_k   = (const float*)d_in[4];
    const float* w_v   = (const float*)d_in[5];
    const float* w_o   = (const float*)d_in[6];
    const float* lng   = (const float*)d_in[7];
    const float* lnb   = (const float*)d_in[8];

    char* ws = (char*)d_ws;
    __bf16* qn  = (__bf16*)(ws);                    // 8 MB  LN(query) bf16
    __bf16* kb  = (__bf16*)(ws + ( 8u << 20));      // 8 MB  key bf16
    __bf16* vb  = (__bf16*)(ws + (16u << 20));      // 8 MB  value bf16
    __bf16* wqb = (__bf16*)(ws + (24u << 20));      // 2 MB
    __bf16* wkb = (__bf16*)(ws + (26u << 20));      // 2 MB
    __bf16* wvb = (__bf16*)(ws + (28u << 20));      // 2 MB
    __bf16* wob = (__bf16*)(ws + (30u << 20));      // 2 MB
    __bf16* Qp  = (__bf16*)(ws + (32u << 20));      // 8 MB  [b,h,s,64] (x1/8)
    __bf16* Kp  = (__bf16*)(ws + (40u << 20));      // 8 MB  [b,h,s,64]
    __bf16* Vt  = (__bf16*)(ws + (48u << 20));      // 8 MB  [b,h,64,s']
    __bf16* oh  = (__bf16*)(ws + (56u << 20));      // 8 MB  attention out [4096,1024]
    float*  mrow    = (float*)(ws + (64u << 20));   // 256 KB
    float*  invlrow = (float*)(ws + (64u << 20) + (256u << 10));  // 256 KB

    float* out  = (float*)d_out;
    float* attn = out + (size_t)MROWS * DMODEL;

    ln_kernel<<<MROWS, 256, 0, stream>>>(query, lng, lnb, qn);
    cast_all<<<12288, 256, 0, stream>>>(key, value, w_q, w_k, w_v, w_o,
                                        kb, vb, wqb, wkb, wvb, wob);

    qkv_proj<<<768, 256, 0, stream>>>(qn, kb, vb, wqb, wkb, wvb, Qp, Kp, Vt);

    attn_stats<<<2048, 256, 0, stream>>>(Qp, Kp, mrow, invlrow);
    attn_pv<<<512, 256, 0, stream>>>(Qp, Kp, Vt, mrow, invlrow, attn, oh);

    out_gemm<<<256, 256, 0, stream>>>(oh, wob, query, out);
}

// Round 8
// 351.010 us; speedup vs baseline: 1.1925x; 1.1925x over previous
//
#include <hip/hip_runtime.h>
#include <hip/hip_bf16.h>

// ---------------------------------------------------------------------------
// MultiheadAttention fused pipeline for MI355X (gfx950)
// B=2, S=S'=2048, H=16, D_MODEL=1024, dk=dv=64
// outputs: out [2,2048,1024] fp32, attn [2,16,2048,2048] fp32 (concat in d_out)
// ---------------------------------------------------------------------------

typedef __bf16 bf16x8 __attribute__((ext_vector_type(8)));
typedef __bf16 bf16x4 __attribute__((ext_vector_type(4)));
typedef float  f32x4  __attribute__((ext_vector_type(4)));
typedef float  f32x16 __attribute__((ext_vector_type(16)));

#define NUM_HEAD 16
#define SEQ 2048
#define DMODEL 1024
#define DK 64
#define MROWS 4096      // B*S

__device__ __forceinline__ void gload_lds16(const void* g, void* l) {
    __builtin_amdgcn_global_load_lds((const __attribute__((address_space(1))) void*)g,
                                     (__attribute__((address_space(3))) void*)l, 16, 0, 0);
}

// ---------------------------------------------------------------------------
// Fused LayerNorm(query)->bf16  +  all fp32->bf16 casts, one dispatch.
// blocks [0,4096): LN row; blocks [4096,16384): cast chunk (float4 each).
// ---------------------------------------------------------------------------
__global__ __launch_bounds__(256) void ln_cast(const float* __restrict__ x,
                                               const float* __restrict__ g,
                                               const float* __restrict__ bt,
                                               __bf16* __restrict__ y,
                                               const float* __restrict__ key,
                                               const float* __restrict__ value,
                                               const float* __restrict__ wq,
                                               const float* __restrict__ wk,
                                               const float* __restrict__ wv,
                                               const float* __restrict__ wo,
                                               __bf16* kb, __bf16* vb, __bf16* wqb,
                                               __bf16* wkb, __bf16* wvb, __bf16* wob) {
    int tid = threadIdx.x;
    if (blockIdx.x < 4096) {
        int row = blockIdx.x;
        __shared__ float red[2][4];
        float4 v = ((const float4*)(x + (size_t)row * DMODEL))[tid];
        float s  = v.x + v.y + v.z + v.w;
        float sq = v.x * v.x + v.y * v.y + v.z * v.z + v.w * v.w;
        #pragma unroll
        for (int o = 32; o; o >>= 1) { s += __shfl_xor(s, o, 64); sq += __shfl_xor(sq, o, 64); }
        int wv_ = tid >> 6;
        if ((tid & 63) == 0) { red[0][wv_] = s; red[1][wv_] = sq; }
        __syncthreads();
        s  = red[0][0] + red[0][1] + red[0][2] + red[0][3];
        sq = red[1][0] + red[1][1] + red[1][2] + red[1][3];
        float mu  = s * (1.0f / DMODEL);
        float var = sq * (1.0f / DMODEL) - mu * mu;
        float rs  = rsqrtf(var + 1e-6f);
        float4 gg = ((const float4*)g)[tid];
        float4 bb = ((const float4*)bt)[tid];
        bf16x4 o;
        o[0] = (__bf16)((v.x - mu) * rs * gg.x + bb.x);
        o[1] = (__bf16)((v.y - mu) * rs * gg.y + bb.y);
        o[2] = (__bf16)((v.z - mu) * rs * gg.z + bb.z);
        o[3] = (__bf16)((v.w - mu) * rs * gg.w + bb.w);
        *(bf16x4*)&y[(size_t)row * DMODEL + tid * 4] = o;
    } else {
        int i = (blockIdx.x - 4096) * 256 + tid;    // float4 index, [0, 3145728)
        const float* src; __bf16* dst; int off;
        if (i < 1048576)      { src = key;   dst = kb;  off = i; }
        else if (i < 2097152) { src = value; dst = vb;  off = i - 1048576; }
        else if (i < 2359296) { src = wq;    dst = wqb; off = i - 2097152; }
        else if (i < 2621440) { src = wk;    dst = wkb; off = i - 2359296; }
        else if (i < 2883584) { src = wv;    dst = wvb; off = i - 2621440; }
        else                  { src = wo;    dst = wob; off = i - 2883584; }
        float4 v = ((const float4*)src)[off];
        bf16x4 o = {(__bf16)v.x, (__bf16)v.y, (__bf16)v.z, (__bf16)v.w};
        *(bf16x4*)&dst[(size_t)off * 4] = o;
    }
}

// ---------------------------------------------------------------------------
// Fused Q/K/V projections, 128x64 tiles -> 3 x 512 = 1536 blocks (6/CU).
// 4 waves as 2x2 (wave tile 64x32), BK=32, global_load_lds staging.
// mode 0: Q -> bf16 [b,h,s,64] scaled 1/8; mode 1: K; mode 2: V transposed.
// ---------------------------------------------------------------------------
__global__ __launch_bounds__(256) void qkv_proj(const __bf16* __restrict__ qn,
                                                const __bf16* __restrict__ kb,
                                                const __bf16* __restrict__ vb,
                                                const __bf16* __restrict__ wqb,
                                                const __bf16* __restrict__ wkb,
                                                const __bf16* __restrict__ wvb,
                                                __bf16* __restrict__ Qp,
                                                __bf16* __restrict__ Kp,
                                                __bf16* __restrict__ Vt) {
    const int Kd = 1024;
    __shared__ __bf16 As[128][32];
    __shared__ __bf16 Bs[64][32];
    int mode = blockIdx.x >> 9;               // 0,1,2
    int t = blockIdx.x & 511;
    int tm = t >> 4, tn = t & 15;             // 32 x 16 tiles (M=4096, N=1024)
    int tid = threadIdx.x, lane = tid & 63, wv = tid >> 6;
    int wr = (wv >> 1) * 64, wc = (wv & 1) * 32;
    int lr = lane & 15, lg = lane >> 4;
    int r0 = tid >> 2, c0 = (tid & 3) * 8;

    const __bf16* A = (mode == 0) ? qn : (mode == 1) ? kb : vb;
    const __bf16* W = (mode == 0) ? wqb : (mode == 1) ? wkb : wvb;

    f32x4 acc[4][2] = {};
    const __bf16* Arow = A + (size_t)(tm * 128) * Kd;
    const __bf16* Brow = W + (size_t)(tn * 64) * Kd;

    for (int kt = 0; kt < Kd; kt += 32) {
        __syncthreads();
        gload_lds16(&Arow[(size_t)r0 * Kd + kt + c0],        &As[r0][c0]);
        gload_lds16(&Arow[(size_t)(r0 + 64) * Kd + kt + c0], &As[r0 + 64][c0]);
        gload_lds16(&Brow[(size_t)r0 * Kd + kt + c0],        &Bs[r0][c0]);
        __syncthreads();
        bf16x8 af[4], bg[2];
        #pragma unroll
        for (int m = 0; m < 4; ++m) af[m] = *(bf16x8*)&As[wr + m * 16 + lr][lg * 8];
        #pragma unroll
        for (int n = 0; n < 2; ++n) bg[n] = *(bf16x8*)&Bs[wc + n * 16 + lr][lg * 8];
        #pragma unroll
        for (int m = 0; m < 4; ++m)
            #pragma unroll
            for (int n = 0; n < 2; ++n)
                acc[m][n] = __builtin_amdgcn_mfma_f32_16x16x32_bf16(af[m], bg[n], acc[m][n], 0, 0, 0);
    }

    if (mode < 2) {
        float scale = (mode == 0) ? 0.125f : 1.0f;
        __bf16* C = (mode == 0) ? Qp : Kp;
        #pragma unroll
        for (int m = 0; m < 4; ++m)
            #pragma unroll
            for (int n = 0; n < 2; ++n)
                #pragma unroll
                for (int r = 0; r < 4; ++r) {
                    int grow = tm * 128 + wr + m * 16 + lg * 4 + r;
                    int gcol = tn * 64 + wc + n * 16 + lr;
                    int b = grow >> 11, ss = grow & 2047, h = gcol >> 6, d = gcol & 63;
                    C[((size_t)(b * NUM_HEAD + h) * SEQ + ss) * DK + d] = (__bf16)(acc[m][n][r] * scale);
                }
    } else {
        #pragma unroll
        for (int m = 0; m < 4; ++m)
            #pragma unroll
            for (int n = 0; n < 2; ++n)
                #pragma unroll
                for (int r = 0; r < 4; ++r) {
                    int grow = tm * 128 + wr + m * 16 + lg * 4 + r;
                    int gcol = tn * 64 + wc + n * 16 + lr;
                    int b = grow >> 11, ss = grow & 2047, h = gcol >> 6, d = gcol & 63;
                    Vt[((size_t)(b * NUM_HEAD + h) * DK + d) * SEQ + ss] = (__bf16)acc[m][n][r];
                }
    }
}

// ---------------------------------------------------------------------------
// Output projection + residual, 128x64 tiles -> 512 blocks (2/CU).
// ---------------------------------------------------------------------------
__global__ __launch_bounds__(256) void out_gemm(const __bf16* __restrict__ A,
                                                const __bf16* __restrict__ Bw,
                                                const float* __restrict__ residual,
                                                float* __restrict__ out) {
    const int Kd = 1024;
    __shared__ __bf16 As[128][32];
    __shared__ __bf16 Bs[64][32];
    int tm = blockIdx.x >> 4, tn = blockIdx.x & 15;
    int tid = threadIdx.x, lane = tid & 63, wv = tid >> 6;
    int wr = (wv >> 1) * 64, wc = (wv & 1) * 32;
    int lr = lane & 15, lg = lane >> 4;
    int r0 = tid >> 2, c0 = (tid & 3) * 8;

    f32x4 acc[4][2] = {};
    const __bf16* Arow = A  + (size_t)(tm * 128) * Kd;
    const __bf16* Brow = Bw + (size_t)(tn * 64) * Kd;

    for (int kt = 0; kt < Kd; kt += 32) {
        __syncthreads();
        gload_lds16(&Arow[(size_t)r0 * Kd + kt + c0],        &As[r0][c0]);
        gload_lds16(&Arow[(size_t)(r0 + 64) * Kd + kt + c0], &As[r0 + 64][c0]);
        gload_lds16(&Brow[(size_t)r0 * Kd + kt + c0],        &Bs[r0][c0]);
        __syncthreads();
        bf16x8 af[4], bg[2];
        #pragma unroll
        for (int m = 0; m < 4; ++m) af[m] = *(bf16x8*)&As[wr + m * 16 + lr][lg * 8];
        #pragma unroll
        for (int n = 0; n < 2; ++n) bg[n] = *(bf16x8*)&Bs[wc + n * 16 + lr][lg * 8];
        #pragma unroll
        for (int m = 0; m < 4; ++m)
            #pragma unroll
            for (int n = 0; n < 2; ++n)
                acc[m][n] = __builtin_amdgcn_mfma_f32_16x16x32_bf16(af[m], bg[n], acc[m][n], 0, 0, 0);
    }

    #pragma unroll
    for (int m = 0; m < 4; ++m)
        #pragma unroll
        for (int n = 0; n < 2; ++n)
            #pragma unroll
            for (int r = 0; r < 4; ++r) {
                int grow = tm * 128 + wr + m * 16 + lg * 4 + r;
                int gcol = tn * 64 + wc + n * 16 + lr;
                size_t idx = (size_t)grow * DMODEL + gcol;
                out[idx] = acc[m][n][r] + residual[idx];
            }
}

// ---------------------------------------------------------------------------
// Attention, flash-style two-phase, swapped QK^T (32x32x16 MFMA) -- the
// round-5 verified kernel + T5 setprio around MFMA clusters.
// Grid 2048 blocks (XCD-chunked), 4 waves; wave wv owns keys [wv*512,+512).
// ---------------------------------------------------------------------------
__global__ __launch_bounds__(256) void attn_kernel(const __bf16* __restrict__ Qp,
                                                   const __bf16* __restrict__ Kp,
                                                   const __bf16* __restrict__ Vt,
                                                   float* __restrict__ attn_out,
                                                   __bf16* __restrict__ out_heads) {
    __shared__ float ored[4][32][68];
    __shared__ float mlred[4][32][2];

    int bid = blockIdx.x;
    int wid = (bid & 7) * 256 + (bid >> 3);   // XCD-chunked: each XCD gets 4 heads
    int bh = wid >> 6;
    int qbase = (wid & 63) * 32;
    int tid = threadIdx.x, lane = tid & 63, wv = tid >> 6;
    int l31 = lane & 31, hi = lane >> 5;

    const __bf16* Qh = Qp + ((size_t)bh * SEQ + qbase) * DK;
    const __bf16* Kh = Kp + (size_t)bh * SEQ * DK;
    const __bf16* Vh = Vt + (size_t)bh * DK * SEQ;

    bf16x8 qf[4];
    #pragma unroll
    for (int s = 0; s < 4; ++s)
        qf[s] = *(const bf16x8*)&Qh[(size_t)l31 * DK + s * 16 + hi * 8];

    int kbase = wv * 512;

    // ---- Phase A: online max / sum over this wave's 512 keys ----
    float m = -1e30f, lsum = 0.f;
    for (int t = 0; t < 16; ++t) {
        int k0 = kbase + t * 32;
        bf16x8 kf[4];
        #pragma unroll
        for (int s = 0; s < 4; ++s)
            kf[s] = *(const bf16x8*)&Kh[(size_t)(k0 + l31) * DK + s * 16 + hi * 8];
        f32x16 d;
        #pragma unroll
        for (int r = 0; r < 16; ++r) d[r] = 0.f;
        __builtin_amdgcn_s_setprio(1);
        #pragma unroll
        for (int s = 0; s < 4; ++s)
            d = __builtin_amdgcn_mfma_f32_32x32x16_bf16(kf[s], qf[s], d, 0, 0, 0);
        __builtin_amdgcn_s_setprio(0);
        float m8[8];
        #pragma unroll
        for (int r = 0; r < 8; ++r) m8[r] = fmaxf(d[r], d[r + 8]);
        #pragma unroll
        for (int r = 0; r < 4; ++r) m8[r] = fmaxf(m8[r], m8[r + 4]);
        float pmax = fmaxf(fmaxf(m8[0], m8[1]), fmaxf(m8[2], m8[3]));
        if (!__all(pmax - m <= 8.0f)) {    // defer-max: rescale rarely
            float nm = fmaxf(m, pmax);
            lsum *= __expf(m - nm);
            m = nm;
        }
        float es[4] = {0.f, 0.f, 0.f, 0.f};
        #pragma unroll
        for (int r = 0; r < 16; ++r) es[r & 3] += __expf(d[r] - m);
        lsum += (es[0] + es[1]) + (es[2] + es[3]);
    }
    {   // merge interleaved key-halves (lane ^ 32, same q)
        float mo = __shfl_xor(m, 32, 64);
        float lo_ = __shfl_xor(lsum, 32, 64);
        float nm = fmaxf(m, mo);
        lsum = lsum * __expf(m - nm) + lo_ * __expf(mo - nm);
        m = nm;
    }
    if (hi == 0) { mlred[wv][l31][0] = m; mlred[wv][l31][1] = lsum; }
    __syncthreads();
    {   // merge across 4 waves (disjoint key ranges)
        float fm = -1e30f;
        #pragma unroll
        for (int w = 0; w < 4; ++w) fm = fmaxf(fm, mlred[w][l31][0]);
        float fl = 0.f;
        #pragma unroll
        for (int w = 0; w < 4; ++w) fl += mlred[w][l31][1] * __expf(mlred[w][l31][0] - fm);
        m = fm;
        lsum = fl;
    }
    float invl = 1.0f / lsum;

    // ---- Phase B: normalized P, direct global write, PV ----
    float* attn_base = attn_out + ((size_t)bh * SEQ + qbase) * SEQ;
    f32x16 o0, o1;
    #pragma unroll
    for (int r = 0; r < 16; ++r) { o0[r] = 0.f; o1[r] = 0.f; }

    for (int t = 0; t < 16; ++t) {
        int k0 = kbase + t * 32;
        bf16x8 kf[4];
        #pragma unroll
        for (int s = 0; s < 4; ++s)
            kf[s] = *(const bf16x8*)&Kh[(size_t)(k0 + l31) * DK + s * 16 + hi * 8];
        f32x16 d;
        #pragma unroll
        for (int r = 0; r < 16; ++r) d[r] = 0.f;
        __builtin_amdgcn_s_setprio(1);
        #pragma unroll
        for (int s = 0; s < 4; ++s)
            d = __builtin_amdgcn_mfma_f32_32x32x16_bf16(kf[s], qf[s], d, 0, 0, 0);
        __builtin_amdgcn_s_setprio(0);

        #pragma unroll
        for (int r = 0; r < 16; ++r) d[r] = __expf(d[r] - m) * invl;

        // direct P write: reg quad q4 = keys k0 + 8*q4 + 4*hi + (0..3), row q=l31
        #pragma unroll
        for (int q4 = 0; q4 < 4; ++q4) {
            f32x4 v4 = {d[4 * q4], d[4 * q4 + 1], d[4 * q4 + 2], d[4 * q4 + 3]};
            *(f32x4*)&attn_base[(size_t)l31 * SEQ + k0 + 8 * q4 + 4 * hi] = v4;
        }

        // pack P to bf16 pair-words: w[i] = keys(reg 2i, 2i+1)
        unsigned int w[8];
        #pragma unroll
        for (int i = 0; i < 8; ++i) {
            union { __bf16 h[2]; unsigned int u; } bw;
            bw.h[0] = (__bf16)d[2 * i];
            bw.h[1] = (__bf16)d[2 * i + 1];
            w[i] = bw.u;
        }
        __builtin_amdgcn_s_setprio(1);
        #pragma unroll
        for (int slot = 0; slot < 2; ++slot) {
            unsigned int w0 = w[4 * slot], w1 = w[4 * slot + 1], w2 = w[4 * slot + 2], w3 = w[4 * slot + 3];
            unsigned int s0 = (unsigned int)__shfl_xor((int)w0, 32, 64);
            unsigned int s1 = (unsigned int)__shfl_xor((int)w1, 32, 64);
            unsigned int s2 = (unsigned int)__shfl_xor((int)w2, 32, 64);
            unsigned int s3 = (unsigned int)__shfl_xor((int)w3, 32, 64);
            union { unsigned int u[4]; bf16x8 v; } pa;
            pa.u[0] = hi ? s2 : w0;
            pa.u[1] = hi ? s3 : w1;
            pa.u[2] = hi ? w2 : s0;
            pa.u[3] = hi ? w3 : s1;
            #pragma unroll
            for (int dvb = 0; dvb < 2; ++dvb) {
                bf16x8 vf = *(const bf16x8*)&Vh[(size_t)(dvb * 32 + l31) * SEQ + k0 + slot * 16 + hi * 8];
                if (dvb == 0) o0 = __builtin_amdgcn_mfma_f32_32x32x16_bf16(pa.v, vf, o0, 0, 0, 0);
                else          o1 = __builtin_amdgcn_mfma_f32_32x32x16_bf16(pa.v, vf, o1, 0, 0, 0);
            }
        }
        __builtin_amdgcn_s_setprio(0);
    }

    // ---- cross-wave O reduce, write out_heads ----
    #pragma unroll
    for (int r = 0; r < 16; ++r) {
        int q = (r & 3) + 8 * (r >> 2) + 4 * hi;
        ored[wv][q][l31]      = o0[r];
        ored[wv][q][32 + l31] = o1[r];
    }
    __syncthreads();
    {
        int q = tid >> 3, d0 = (tid & 7) * 8;
        float s[8];
        #pragma unroll
        for (int j = 0; j < 8; ++j) s[j] = 0.f;
        #pragma unroll
        for (int w = 0; w < 4; ++w)
            #pragma unroll
            for (int j = 0; j < 8; ++j) s[j] += ored[w][q][d0 + j];
        int b = bh >> 4, h = bh & 15;
        bf16x8 ov;
        #pragma unroll
        for (int j = 0; j < 8; ++j) ov[j] = (__bf16)s[j];
        *(bf16x8*)&out_heads[((size_t)(b * SEQ + qbase + q)) * DMODEL + h * DK + d0] = ov;
    }
}

// ---------------------------------------------------------------------------
extern "C" void kernel_launch(void* const* d_in, const int* in_sizes, int n_in,
                              void* d_out, int out_size, void* d_ws, size_t ws_size,
                              hipStream_t stream) {
    const float* query = (const float*)d_in[0];
    const float* key   = (const float*)d_in[1];
    const float* value = (const float*)d_in[2];
    const float* w_q   = (const float*)d_in[3];
    const float* w_k   = (const float*)d_in[4];
    const float* w_v   = (const float*)d_in[5];
    const float* w_o   = (const float*)d_in[6];
    const float* lng   = (const float*)d_in[7];
    const float* lnb   = (const float*)d_in[8];

    char* ws = (char*)d_ws;
    __bf16* qn  = (__bf16*)(ws);                    // 8 MB  LN(query) bf16
    __bf16* kb  = (__bf16*)(ws + ( 8u << 20));      // 8 MB  key bf16
    __bf16* vb  = (__bf16*)(ws + (16u << 20));      // 8 MB  value bf16
    __bf16* wqb = (__bf16*)(ws + (24u << 20));      // 2 MB
    __bf16* wkb = (__bf16*)(ws + (26u << 20));      // 2 MB
    __bf16* wvb = (__bf16*)(ws + (28u << 20));      // 2 MB
    __bf16* wob = (__bf16*)(ws + (30u << 20));      // 2 MB
    __bf16* Qp  = (__bf16*)(ws + (32u << 20));      // 8 MB  [b,h,s,64] (x1/8)
    __bf16* Kp  = (__bf16*)(ws + (40u << 20));      // 8 MB  [b,h,s,64]
    __bf16* Vt  = (__bf16*)(ws + (48u << 20));      // 8 MB  [b,h,64,s']
    __bf16* oh  = (__bf16*)(ws + (56u << 20));      // 8 MB  attention out [4096,1024]

    float* out  = (float*)d_out;
    float* attn = out + (size_t)MROWS * DMODEL;

    ln_cast<<<16384, 256, 0, stream>>>(query, lng, lnb, qn,
                                       key, value, w_q, w_k, w_v, w_o,
                                       kb, vb, wqb, wkb, wvb, wob);

    qkv_proj<<<1536, 256, 0, stream>>>(qn, kb, vb, wqb, wkb, wvb, Qp, Kp, Vt);

    attn_kernel<<<2048, 256, 0, stream>>>(Qp, Kp, Vt, attn, oh);

    out_gemm<<<512, 256, 0, stream>>>(oh, wob, query, out);
}